// Round 11
// baseline (535.568 us; speedup 1.0000x reference)
//
#include <hip/hip_runtime.h>
#include <hip/hip_bf16.h>
#include <math.h>

// Problem: B=256, N_SRC=10, NMC=16, L=128. out[b,ch,y,x]: ch<16 = 1-z,
// ch>=16 = z. PASSED R8/R10 (absmax 0.0). R11 = split into
//   (A) pure constant fill (one block/plane, no preamble-before-store
//       coupling: no LDS, no syncthreads, no lows/highs reads)
//   (B) 2560-thread scatter-fix patching 2 cells per source point.
// Numerics (per-op ml_dtypes bf16 rounding) and host binding identical to
// the passing rounds.
#define NSRC 10
#define NMC  16
#define LSZ  128
#define PLANE (LSZ * LSZ)   // 16384

typedef unsigned int uintv4 __attribute__((ext_vector_type(4)));
typedef float        fltv4  __attribute__((ext_vector_type(4)));

__device__ __forceinline__ float bf16f(unsigned short h) {
    union { unsigned int u; float f; } c;
    c.u = ((unsigned int)h) << 16;
    return c.f;
}

// f32 -> bf16 round-to-nearest-even, returned as f32 (ml_dtypes semantics).
__device__ __forceinline__ float bf16r(float f) {
    union { float f; unsigned int u; } c;
    c.f = f;
    unsigned int lsb = (c.u >> 16) & 1u;
    c.u += 0x7FFFu + lsb;
    c.u &= 0xFFFF0000u;
    return c.f;
}

// Grid-uniform input-dtype probe: bf16 coord -> batch-0 mass columns decode
// into [0.5,2048]; f32 coord -> probes are random mantissa halves (fails whp).
__device__ __forceinline__ bool detect_bf16(const unsigned short* cu) {
    bool isbf = true;
    #pragma unroll
    for (int j = 2; j < 3 * NSRC; j += 3) {
        float v = bf16f(cu[j]);
        if (!(v >= 0.5f && v <= 2048.0f)) isbf = false;
    }
    return isbf;
}

// ---------- Kernel A: constant fill, one block per output plane ----------
// Block-uniform value, no LDS, no barrier: structurally a memset at the
// rocclr-fill rate. ch = plane % 32; ch<16 -> 1.0 pattern, else 0.0.
extern "C" __global__ __launch_bounds__(256)
void CustomParameterTransform_2491081031994_fill(
    const void* __restrict__ coord_v,
    void* __restrict__ out_v)
{
    const bool isbf = detect_bf16((const unsigned short*)coord_v);
    const int pid = blockIdx.x;          // b*32 + ch
    const bool ones = (pid & 31) < 16;

    if (isbf) {
        unsigned short* p = (unsigned short*)out_v + (size_t)pid * PLANE;
        const unsigned int w = ones ? 0x3F803F80u : 0u;
        const uintv4 val = { w, w, w, w };
        // 256 thr x 8 bf16 (16 B) = 2048 elems/iter -> 8 iters per plane.
        for (int base = threadIdx.x * 8; base < PLANE; base += 256 * 8)
            *(uintv4*)(p + base) = val;
    } else {
        float* p = (float*)out_v + (size_t)pid * PLANE;
        const float w = ones ? 1.0f : 0.0f;
        const fltv4 val = { w, w, w, w };
        for (int base = threadIdx.x * 4; base < PLANE; base += 256 * 4)
            *(fltv4*)(p + base) = val;
    }
}

// ---------- Kernel B: scatter fix, one thread per source point ----------
// Patches out[b][mi][yi][xi] = 0 (1-z plane) and out[b][16+mi][yi][xi] = 1.
// Duplicate (b,mi,yi,xi) across sources write identical values (benign).
extern "C" __global__ __launch_bounds__(256)
void CustomParameterTransform_2491081031994_scatter(
    const void* __restrict__ coord_v,
    const void* __restrict__ pA,      // one of {lows, highs}
    const void* __restrict__ pB,      // the other
    void* __restrict__ out_v,
    int total)                        // nb * NSRC
{
    const int tid = blockIdx.x * 256 + threadIdx.x;
    if (tid >= total) return;

    const unsigned short* cu = (const unsigned short*)coord_v;
    const bool isbf = detect_bf16(cu);

    // lows/highs classified by element [2] (0.0 vs 3.0) — uniform.
    float a2, b2;
    if (isbf) {
        a2 = bf16f(((const unsigned short*)pA)[2]);
        b2 = bf16f(((const unsigned short*)pB)[2]);
    } else {
        a2 = ((const float*)pA)[2];
        b2 = ((const float*)pB)[2];
    }
    const void* lows_v  = (a2 < b2) ? pA : pB;
    const void* highs_v = (a2 < b2) ? pB : pA;

    const int b = tid / NSRC;
    const int s = tid - b * NSRC;

    int xi, yi, mi;
    if (isbf) {
        const unsigned short* t = cu + b * (3 * NSRC) + s * 3;
        float x    = bf16f(t[0]);
        float y    = bf16f(t[1]);
        float mass = bf16f(t[2]);
        const unsigned short* lw = (const unsigned short*)lows_v;
        const unsigned short* hg = (const unsigned short*)highs_v;
        float lo0 = bf16f(lw[0]), lo1 = bf16f(lw[1]), lo2 = bf16f(lw[2]);
        float hi0 = bf16f(hg[0]), hi1 = bf16f(hg[1]), hi2 = bf16f(hg[2]);
        // ml_dtypes chain, per-op bf16 rounding (identical to R8/R10):
        float d0 = bf16r(hi0 - lo0);
        float d1 = bf16r(hi1 - lo1);
        float d2 = bf16r(hi2 - lo2);
        float xg = bf16r(bf16r(x - lo0) / d0);
        float yg = bf16r(bf16r(y - lo1) / d1);
        float l10 = bf16r((float)log10((double)mass));
        float mg  = bf16r(bf16r(l10 - lo2) / d2);
        xi = (int)floorf(bf16r(xg * (float)LSZ));
        yi = (int)floorf(bf16r(yg * (float)LSZ));
        mi = (int)floorf(bf16r(mg * (float)NMC));
    } else {
        const float* cf = (const float*)coord_v;
        const float* t = cf + b * (3 * NSRC) + s * 3;
        const float* lw = (const float*)lows_v;
        const float* hg = (const float*)highs_v;
        float xg = (t[0] - lw[0]) / (hg[0] - lw[0]);
        float yg = (t[1] - lw[1]) / (hg[1] - lw[1]);
        float mg = ((float)log10((double)t[2]) - lw[2]) / (hg[2] - lw[2]);
        xi = (int)floorf(xg * (float)LSZ);
        yi = (int)floorf(yg * (float)LSZ);
        mi = (int)floorf(mg * (float)NMC);
    }
    // OOB dropped (JAX scatter semantics).
    if ((unsigned)mi >= (unsigned)NMC ||
        (unsigned)xi >= (unsigned)LSZ ||
        (unsigned)yi >= (unsigned)LSZ) return;

    const size_t cell = ((size_t)b * (2 * NMC) + mi) * PLANE + yi * LSZ + xi;
    if (isbf) {
        unsigned short* o = (unsigned short*)out_v;
        o[cell] = 0;                                   // 1-z plane -> 0
        o[cell + (size_t)NMC * PLANE] = 0x3F80;        // z plane   -> 1
    } else {
        float* o = (float*)out_v;
        o[cell] = 0.0f;
        o[cell + (size_t)NMC * PLANE] = 1.0f;
    }
}

// Validate candidate size vector {..,30*nb,..,3,..,3,..,1,1}; ALL entries
// >= 1 rejects the int32 view of 64-bit sizes (contains zeros).
static bool try_bind(const long* v, int n, int& ic, int& iA, int& iB, long& nbc) {
    for (int i = 0; i < n; ++i) if (v[i] < 1) return false;
    int lc = -1, a = -1, b = -1;
    for (int i = 0; i < n; ++i)
        if (v[i] >= 30 && v[i] % 30 == 0) { if (lc >= 0) return false; lc = i; }
    if (lc < 0) return false;
    for (int i = 0; i < n; ++i) {
        if (i == lc) continue;
        if (v[i] == 3) { if (a < 0) a = i; else if (b < 0) b = i; else return false; }
    }
    if (a < 0 || b < 0) return false;
    ic = lc; iA = a; iB = b; nbc = v[lc] / 30;
    return true;
}

extern "C" void kernel_launch(void* const* d_in, const int* in_sizes, int n_in,
                              void* d_out, int out_size, void* d_ws, size_t ws_size,
                              hipStream_t stream) {
    int ic = 0, iA = 1, iB = 2;       // dict-order fallback
    long nbc = -1;
    const int n = (n_in > 8) ? 8 : (n_in > 0 ? n_in : 0);
    long v[8];
    bool ok = false;
    if (n >= 3) {
        for (int i = 0; i < n; ++i) v[i] = (long)in_sizes[i];
        ok = try_bind(v, n, ic, iA, iB, nbc);              // int32 sizes
        if (!ok) {
            const long long* s64 = (const long long*)in_sizes;
            for (int i = 0; i < n; ++i) v[i] = (long)s64[i];
            ok = try_bind(v, n, ic, iA, iB, nbc);          // int64 sizes
        }
        if (!ok) { ic = 0; iA = 1; iB = 2; nbc = -1; }     // dict order
    }

    long nb_out = (out_size > 0) ? (long)out_size / (2L * NMC * PLANE) : -1;
    long nb = (nbc > 0) ? nbc : nb_out;
    if (nbc > 0 && nb_out > 0 && nb_out < nb) nb = nb_out;
    if (nb <= 0) nb = 1;

    // A: constant fill — one block per plane (nb * 2*NMC planes).
    dim3 gfill((unsigned)(nb * 2 * NMC));
    CustomParameterTransform_2491081031994_fill<<<gfill, dim3(256), 0, stream>>>(
        d_in[ic], d_out);

    // B: scatter fix — one thread per source point.
    int total = (int)(nb * NSRC);
    dim3 gsc((unsigned)((total + 255) / 256));
    CustomParameterTransform_2491081031994_scatter<<<gsc, dim3(256), 0, stream>>>(
        d_in[ic], d_in[iA], d_in[iB], d_out, total);
}